// Round 12
// baseline (322.749 us; speedup 1.0000x reference)
//
#include <hip/hip_runtime.h>
#include <hip/hip_bf16.h>
#include <stdint.h>

typedef __attribute__((ext_vector_type(8))) short s16x8;    // bf16 MFMA A/B frag (4 VGPRs)
typedef __attribute__((ext_vector_type(4))) float f32x4;    // MFMA C/D frag
typedef __attribute__((ext_vector_type(4))) unsigned short us4;

// ---- bf16 round-to-nearest-even (inputs are finite normals) ----
__device__ inline unsigned short bf_rne(float f) {
    union { float f; uint32_t u; } v; v.f = f;
    uint32_t u = v.u;
    u += 0x7FFFu + ((u >> 16) & 1u);
    return (unsigned short)(u >> 16);
}

// async global->LDS, 16B per lane; LDS dst is wave-uniform base + lane*16
#define GLD_LDS16(gp, lp)                                                     \
    __builtin_amdgcn_global_load_lds(                                         \
        (const __attribute__((address_space(1))) void*)(gp),                  \
        (__attribute__((address_space(3))) void*)(lp), 16, 0, 0)

// generic (__shared__) pointer -> 32-bit LDS byte offset for ds_read vaddr
#define LDSOFF(p) ((unsigned)(uintptr_t)(__attribute__((address_space(3))) const void*)(p))

// ---------------- Fused prologue (unchanged: at memory roofline) ----------------
__global__ __launch_bounds__(256) void prologue_kernel(
    const float4* __restrict__ x4, us4* __restrict__ xbf4,
    const float4* __restrict__ W4,
    const float4* __restrict__ A4,   // [16][1024] float4
    const float* __restrict__ B,     // [4096][16]
    const float* __restrict__ mag,   // [4096]
    unsigned short* __restrict__ wbf,
    float* __restrict__ scale) {
    const int tid = threadIdx.x;
    if (blockIdx.x < 512) {
        const int m0 = blockIdx.x * 8;
        __shared__ float Bs[8][16];
        __shared__ float red[32];
        if (tid < 128) Bs[tid >> 4][tid & 15] = B[m0 * 16 + tid];
        __syncthreads();
        float ss[8] = {};
        for (int c = tid; c < 1024; c += 256) {
            float4 a[16];
#pragma unroll
            for (int r = 0; r < 16; ++r) a[r] = A4[r * 1024 + c];
#pragma unroll
            for (int i = 0; i < 8; ++i) {
                float4 w = W4[(size_t)(m0 + i) * 1024 + c];
#pragma unroll
                for (int r = 0; r < 16; ++r) {
                    const float br = Bs[i][r];
                    w.x += br * a[r].x; w.y += br * a[r].y;
                    w.z += br * a[r].z; w.w += br * a[r].w;
                }
                ss[i] += w.x * w.x + w.y * w.y + w.z * w.z + w.w * w.w;
                us4 o; o[0] = bf_rne(w.x); o[1] = bf_rne(w.y);
                o[2] = bf_rne(w.z); o[3] = bf_rne(w.w);
                *(us4*)&wbf[(size_t)(m0 + i) * 4096 + c * 4] = o;
            }
        }
        const int lane = tid & 63, wv = tid >> 6;
#pragma unroll
        for (int i = 0; i < 8; ++i) {
            float v = ss[i];
#pragma unroll
            for (int off = 32; off > 0; off >>= 1) v += __shfl_down(v, off, 64);
            if (lane == 0) red[wv * 8 + i] = v;
        }
        __syncthreads();
        if (tid < 8) {
            float tot = red[tid] + red[8 + tid] + red[16 + tid] + red[24 + tid];
            scale[m0 + tid] = mag[m0 + tid] / sqrtf(tot);
        }
    } else {
        const size_t base = (size_t)(blockIdx.x - 512) * 1024 + tid;
#pragma unroll
        for (int j = 0; j < 4; ++j) {
            const size_t idx = base + j * 256;
            float4 a = x4[idx];
            us4 o;
            o[0] = bf_rne(a.x); o[1] = bf_rne(a.y);
            o[2] = bf_rne(a.z); o[3] = bf_rne(a.w);
            xbf4[idx] = o;
        }
    }
}

// ---------------- GEMM: C[8192][4096] = xbf @ wbf^T * scale ----------------
// 256x256 tile, BK=64, 8 waves (2M x 4N), 16x16x32 MFMA, R5 datapath
// (A+B LDS-staged, XOR swizzle, precomputed inline-asm ds_read, 0 conflicts),
// 4 barriers/tile (R10: fewer is worse).
// R12 = R11's cross-window read-ahead with LIFETIME-CORRECT slots (R11 bug:
// af[] holds ONE mh-half; W3's af refill clobbered af1 before Q10 used it).
// Window plan per tile t (buf d, other buf d^1; Q-order Q00,Q01,Q11,Q10):
//  W1: LGW0 [drains af0(t),bfx0(t), issued t-1 W4]; stage(t+1)x4 -> d^1;
//      Q00(af0,bfx0); read bfx1(t); BAR
//  W2: LGW0 [bfx1]; Q01(af0,bfx1); read af1(t) [af0 dead]; BAR
//  W3: LGW0 [af1]; Q11(af1,bfx1); VMW0; BAR  [stages 2 windows old; first
//      d^1 read is W4 -> RAW safe after this BAR]
//  W4: Q10(af1,bfx0) [operands drained W3/W1; W3's SB0 fences rule-18
//      hoisting]; read af0(t+1)+bfx0(t+1) from d^1 [post-Q10-issue overwrite,
//      R7-proven pattern]; BAR
// Lifetimes: af0->{Q00,Q01} refill W2; af1->{Q11,Q10} refill W4; bfx0->
// {Q00,Q10} refill W4; bfx1->{Q01,Q11} refill next W1. All refills follow
// their block's last consumer.
// WAR on stage@W1 -> d^1: d^1's last readers = t-1 W1/W2 reads, drained by
// t-1 W2/W3 LGW0, >=2 BARs before t W1. RAW: W4 d^1 reads follow VMW0+BAR.
// Per-acc-cell MFMA order unchanged from R5 -> bit-identical output.
#define FENCE() asm volatile("" ::: "memory")
#define BAR()   do { FENCE(); __builtin_amdgcn_s_barrier(); FENCE(); } while (0)
#define VMW(n)  asm volatile("s_waitcnt vmcnt(" #n ")" ::: "memory")
#define LGW(n)  asm volatile("s_waitcnt lgkmcnt(" #n ")" ::: "memory")
#define SB0()   __builtin_amdgcn_sched_barrier(0)
#define PRIO1() __builtin_amdgcn_s_setprio(1)
#define PRIO0() __builtin_amdgcn_s_setprio(0)

// precomputed-address LDS read: vaddr VGPR + literal offset immediate
#define DSR(dst, va, IMM) \
    asm volatile("ds_read_b128 %0, %1 offset:" #IMM : "=v"(dst) : "v"(va))

__global__ __launch_bounds__(512, 2) void dora_gemm(
    const unsigned short* __restrict__ xbf,   // [8192][4096] bf16
    const unsigned short* __restrict__ wbf,   // [4096][4096] bf16
    const float* __restrict__ scale,          // [4096]
    float* __restrict__ out) {                // [8192][4096] fp32
    __shared__ __align__(16) unsigned short As[2][256 * 64];
    __shared__ __align__(16) unsigned short Bs[2][256 * 64];

    const int tid  = threadIdx.x;
    const int lane = tid & 63;
    const int w    = tid >> 6;     // wave 0..7
    const int wm   = w >> 2;       // 0..1
    const int wn   = w & 3;        // 0..3
    const int q    = lane >> 4;
    const int c15  = lane & 15;

    // XCD mapping: 8 XCDs x 64 blocks; each XCD owns an 8M x 8N tile square
    // (bijective over the 32x16 grid); M sweeps fastest within the square.
    const int bid = blockIdx.x;
    const int xcd = bid & 7, sub = bid >> 3;
    const int tileM = (((xcd & 3) << 3) | (sub & 7)) << 8;   // 0..31 * 256
    const int tileN = (((xcd >> 2) << 3) | (sub >> 3)) << 8; // 0..15 * 256

    // staging: thread t, load j covers linear chunk c = j*512 + t of a half-tile
    // (128 rows x 64 bf16). row-in-half = c>>3, phys 16B chunk = c&7; XOR swizzle:
    // phys chunk p of row r holds logical chunk p ^ (r&7) -> pre-swizzled source.
    const int r0 = tid >> 3;              // 0..63
    const int lc = (tid & 7) ^ (r0 & 7);
    const size_t aoff = (size_t)(tileM + r0) * 4096 + lc * 8;
    const size_t boff = (size_t)(tileN + r0) * 4096 + lc * 8;
    const int ld0 = (w * 64) * 8;         // shorts; wave-uniform LDS base, j=0
    const int ld1 = (512 + w * 64) * 8;   // j=1 (+64 rows)

#define STAGE_A(d, h, k0) do {                                                            \
    GLD_LDS16(xbf + aoff + (size_t)((h) * 128) * 4096 + (k0),      &As[d][(h) * 8192 + ld0]); \
    GLD_LDS16(xbf + aoff + (size_t)((h) * 128 + 64) * 4096 + (k0), &As[d][(h) * 8192 + ld1]); \
} while (0)
#define STAGE_B(d, h, k0) do {                                                            \
    GLD_LDS16(wbf + boff + (size_t)((h) * 128) * 4096 + (k0),      &Bs[d][(h) * 8192 + ld0]); \
    GLD_LDS16(wbf + boff + (size_t)((h) * 128 + 64) * 4096 + (k0), &Bs[d][(h) * 8192 + ld1]); \
} while (0)

    // Precomputed ds_read base addresses (buf0, mh0/nh0). For every frag,
    // row&7 == c15&7, so phys = (kc*4+q)^(c15&7) is row-independent.
    const int rb = c15 & 7;
    unsigned aA[4][2], aB[2][2];
#pragma unroll
    for (int mt = 0; mt < 4; ++mt)
#pragma unroll
        for (int kc = 0; kc < 2; ++kc)
            aA[mt][kc] = LDSOFF(&As[0][(wm * 64 + mt * 16 + c15) * 64 +
                                       ((kc * 4 + q) ^ rb) * 8]);
#pragma unroll
    for (int nt = 0; nt < 2; ++nt)
#pragma unroll
        for (int kc = 0; kc < 2; ++kc)
            aB[nt][kc] = LDSOFF(&Bs[0][(wn * 32 + nt * 16 + c15) * 64 +
                                       ((kc * 4 + q) ^ rb) * 8]);

    s16x8 af[4][2];      // A frags [mt][kc], current mh (ONE half at a time)
    s16x8 bfx[2][2][2];  // B frags [nh][nt][kc]
    f32x4 acc[8][4] = {};

    // IMM encodes (buffer, half): buf = +32768, mh/nh = +16384
#define RD_A(IMM) do {                                                        \
    DSR(af[0][0], aA[0][0], IMM); DSR(af[0][1], aA[0][1], IMM);               \
    DSR(af[1][0], aA[1][0], IMM); DSR(af[1][1], aA[1][1], IMM);               \
    DSR(af[2][0], aA[2][0], IMM); DSR(af[2][1], aA[2][1], IMM);               \
    DSR(af[3][0], aA[3][0], IMM); DSR(af[3][1], aA[3][1], IMM); } while (0)
#define RD_B(nh, IMM) do {                                                    \
    DSR(bfx[nh][0][0], aB[0][0], IMM); DSR(bfx[nh][0][1], aB[0][1], IMM);     \
    DSR(bfx[nh][1][0], aB[1][0], IMM); DSR(bfx[nh][1][1], aB[1][1], IMM); } while (0)

#define MFMA_Q(mh, nh) do {                                                   \
    _Pragma("unroll") for (int mt = 0; mt < 4; ++mt)                          \
    _Pragma("unroll") for (int nt = 0; nt < 2; ++nt)                          \
    _Pragma("unroll") for (int kc = 0; kc < 2; ++kc)                          \
        acc[(mh) * 4 + mt][(nh) * 2 + nt] =                                   \
            __builtin_amdgcn_mfma_f32_16x16x32_bf16(                          \
                af[mt][kc], bfx[nh][nt][kc],                                  \
                acc[(mh) * 4 + mt][(nh) * 2 + nt], 0, 0, 0);                  \
} while (0)

    // Read-ahead tile body. IB1/IA1 = buf d IMMs (bfx1/af1 of tile t);
    // IAN/IBN = buf d^1 IMMs (af0/bfx0 of tile t+1). DD = d^1, KN = k(t+1).
#define TILE(IB1, IA1, IAN, IBN, DD, KN) do {                                 \
    /* W1: Q00(af0,bfx0) */                                                   \
    LGW(0); SB0();                                                            \
    STAGE_A(DD, 0, KN); STAGE_B(DD, 0, KN);                                   \
    STAGE_B(DD, 1, KN); STAGE_A(DD, 1, KN);                                   \
    PRIO1(); MFMA_Q(0, 0); PRIO0();                                           \
    RD_B(1, IB1);                                                             \
    BAR();                                                                    \
    /* W2: Q01(af0,bfx1) */                                                   \
    LGW(0); SB0();                                                            \
    PRIO1(); MFMA_Q(0, 1); PRIO0();                                           \
    RD_A(IA1);                                                                \
    BAR();                                                                    \
    /* W3: Q11(af1,bfx1); stages (issued W1) drained + made visible */        \
    LGW(0); SB0();                                                            \
    PRIO1(); MFMA_Q(1, 1); PRIO0();                                           \
    VMW(0); BAR();                                                            \
    /* W4: Q10(af1,bfx0); then prefetch next-tile af0,bfx0 from buf d^1 */    \
    PRIO1(); MFMA_Q(1, 0); PRIO0();                                           \
    RD_A(IAN); RD_B(0, IBN);                                                  \
    BAR();                                                                    \
} while (0)

    // prologue: stage tile0 -> buf0; drain; preload af0(0),bfx0(0)
    // (emulates "t-1 W4" so the first W1's LGW0 has its reads in flight).
    STAGE_A(0, 0, 0); STAGE_B(0, 0, 0); STAGE_B(0, 1, 0); STAGE_A(0, 1, 0);
    VMW(0); BAR();
    RD_A(0); RD_B(0, 0);

    // tiles 0..61 in pairs; tile t stages tile t+1 (KN=(t+1)*64).
    for (int kn = 64; kn <= 3904; kn += 128) {
        TILE(16384, 16384, 32768, 32768, 1, kn);       // even tile (buf0)
        TILE(49152, 49152, 0, 0, 0, kn + 64);          // odd tile  (buf1)
    }
    // tile 62 (buf0): stages tile 63 -> buf1; W4 prefetches af0(63),bfx0(63)
    TILE(16384, 16384, 32768, 32768, 1, 4032);
    // tile 63 (buf1) peel: own-wave reads only, no stages -> no barriers
    LGW(0); SB0();
    PRIO1(); MFMA_Q(0, 0); PRIO0();
    RD_B(1, 49152);
    LGW(0); SB0();
    PRIO1(); MFMA_Q(0, 1); PRIO0();
    RD_A(49152);
    LGW(0); SB0();
    PRIO1(); MFMA_Q(1, 1); MFMA_Q(1, 0); PRIO0();

    // epilogue: C/D layout col=lane&15, row=(lane>>4)*4+reg ; scale by mag/norm
#pragma unroll
    for (int nh = 0; nh < 2; ++nh)
#pragma unroll
    for (int nt = 0; nt < 2; ++nt) {
        const int col = tileN + nh * 128 + wn * 32 + nt * 16 + c15;
        const float s = scale[col];
#pragma unroll
        for (int mh = 0; mh < 2; ++mh)
#pragma unroll
        for (int mt = 0; mt < 4; ++mt) {
            const int row0 = tileM + mh * 128 + wm * 64 + mt * 16 + q * 4;
#pragma unroll
            for (int r = 0; r < 4; ++r)
                out[(size_t)(row0 + r) * 4096 + col] = acc[mh * 4 + mt][nh * 2 + nt][r] * s;
        }
    }
}

extern "C" void kernel_launch(void* const* d_in, const int* in_sizes, int n_in,
                              void* d_out, int out_size, void* d_ws, size_t ws_size,
                              hipStream_t stream) {
    const float* x   = (const float*)d_in[0];   // [4,2048,4096]
    const float* W   = (const float*)d_in[1];   // [4096,4096]
    const float* A   = (const float*)d_in[2];   // [16,4096]
    const float* B   = (const float*)d_in[3];   // [4096,16]
    const float* mag = (const float*)d_in[4];   // [4096]
    float* out = (float*)d_out;

    const size_t XBF_BYTES = (size_t)8192 * 4096 * 2;  // 67,108,864
    const size_t WBF_BYTES = (size_t)4096 * 4096 * 2;  // 33,554,432
    const size_t NEEDED = XBF_BYTES + WBF_BYTES + 4096 * sizeof(float);
    if (ws_size < NEEDED) return;

    unsigned short* xbf = (unsigned short*)d_ws;
    unsigned short* wbf = (unsigned short*)((char*)d_ws + XBF_BYTES);
    float* scale = (float*)((char*)d_ws + XBF_BYTES + WBF_BYTES);

    prologue_kernel<<<8704, 256, 0, stream>>>((const float4*)x, (us4*)xbf,
                                              (const float4*)W, (const float4*)A,
                                              B, mag, wbf, scale);
    dora_gemm<<<512, 512, 0, stream>>>(xbf, wbf, scale, out);
}

// Round 13
// 303.831 us; speedup vs baseline: 1.0623x; 1.0623x over previous
//
#include <hip/hip_runtime.h>
#include <hip/hip_bf16.h>
#include <stdint.h>

typedef __attribute__((ext_vector_type(8))) short s16x8;    // bf16 MFMA A/B frag (4 VGPRs)
typedef __attribute__((ext_vector_type(4))) float f32x4;    // MFMA C/D frag
typedef __attribute__((ext_vector_type(4))) unsigned short us4;

// ---- bf16 round-to-nearest-even (inputs are finite normals) ----
__device__ inline unsigned short bf_rne(float f) {
    union { float f; uint32_t u; } v; v.f = f;
    uint32_t u = v.u;
    u += 0x7FFFu + ((u >> 16) & 1u);
    return (unsigned short)(u >> 16);
}

// non-temporal 16B fp32 load (single-use streams: x-fp32, W-fp32) — keeps
// L3 for the hot bf16 operands instead of 335MB of once-touched data.
__device__ inline float4 ntload4(const float4* p) {
    f32x4 v = __builtin_nontemporal_load((const f32x4*)p);
    return *(float4*)&v;
}

// async global->LDS, 16B per lane; LDS dst is wave-uniform base + lane*16
#define GLD_LDS16(gp, lp)                                                     \
    __builtin_amdgcn_global_load_lds(                                         \
        (const __attribute__((address_space(1))) void*)(gp),                  \
        (__attribute__((address_space(3))) void*)(lp), 16, 0, 0)

// generic (__shared__) pointer -> 32-bit LDS byte offset for ds_read vaddr
#define LDSOFF(p) ((unsigned)(uintptr_t)(__attribute__((address_space(3))) const void*)(p))

// ---------------- Fused prologue ----------------
// blocks [0,512):    prep — adapted = W + B@A -> bf16, scale = mag/rownorm
// blocks [512,8704): cvt — x fp32 -> bf16. NT loads on x/W (read exactly once).
__global__ __launch_bounds__(256) void prologue_kernel(
    const float4* __restrict__ x4, us4* __restrict__ xbf4,
    const float4* __restrict__ W4,
    const float4* __restrict__ A4,   // [16][1024] float4 (reused 512x: cached)
    const float* __restrict__ B,     // [4096][16]
    const float* __restrict__ mag,   // [4096]
    unsigned short* __restrict__ wbf,
    float* __restrict__ scale) {
    const int tid = threadIdx.x;
    if (blockIdx.x < 512) {
        const int m0 = blockIdx.x * 8;
        __shared__ float Bs[8][16];
        __shared__ float red[32];
        if (tid < 128) Bs[tid >> 4][tid & 15] = B[m0 * 16 + tid];
        __syncthreads();
        float ss[8] = {};
        for (int c = tid; c < 1024; c += 256) {
            float4 a[16];
#pragma unroll
            for (int r = 0; r < 16; ++r) a[r] = A4[r * 1024 + c];
#pragma unroll
            for (int i = 0; i < 8; ++i) {
                float4 w = ntload4(&W4[(size_t)(m0 + i) * 1024 + c]);
#pragma unroll
                for (int r = 0; r < 16; ++r) {
                    const float br = Bs[i][r];
                    w.x += br * a[r].x; w.y += br * a[r].y;
                    w.z += br * a[r].z; w.w += br * a[r].w;
                }
                ss[i] += w.x * w.x + w.y * w.y + w.z * w.z + w.w * w.w;
                us4 o; o[0] = bf_rne(w.x); o[1] = bf_rne(w.y);
                o[2] = bf_rne(w.z); o[3] = bf_rne(w.w);
                *(us4*)&wbf[(size_t)(m0 + i) * 4096 + c * 4] = o;
            }
        }
        const int lane = tid & 63, wv = tid >> 6;
#pragma unroll
        for (int i = 0; i < 8; ++i) {
            float v = ss[i];
#pragma unroll
            for (int off = 32; off > 0; off >>= 1) v += __shfl_down(v, off, 64);
            if (lane == 0) red[wv * 8 + i] = v;
        }
        __syncthreads();
        if (tid < 8) {
            float tot = red[tid] + red[8 + tid] + red[16 + tid] + red[24 + tid];
            scale[m0 + tid] = mag[m0 + tid] / sqrtf(tot);
        }
    } else {
        const size_t base = (size_t)(blockIdx.x - 512) * 1024 + tid;
#pragma unroll
        for (int j = 0; j < 4; ++j) {
            const size_t idx = base + j * 256;
            float4 a = ntload4(&x4[idx]);
            us4 o;
            o[0] = bf_rne(a.x); o[1] = bf_rne(a.y);
            o[2] = bf_rne(a.z); o[3] = bf_rne(a.w);
            xbf4[idx] = o;
        }
    }
}

// ---------------- GEMM: C[8192][4096] = xbf @ wbf^T * scale ----------------
// R5-best body (226.6us measured): 256x256 tile, BK=64, 8 waves (2M x 4N),
// 16x16x32 MFMA, precomputed-address inline-asm ds_read_b128 (0 conflicts),
// ONE barrier per phase (stage at phase s is WAR-safe if region's last reader
// is <= s-2: a wave crossing BAR_{p+1} has executed its phase-p LGW0).
// R13 adds ONLY non-temporal C stores (C is never re-read).
// Stage ledger (iter i, t0=2i, t1=2i+1):
//   ph1: B1(t1)->buf1   [buf1.B1 last read ph6 of iter i-1; +3]
//   ph2: A1(t1)->buf1   [last read ph7 i-1; +3]
//   ph3: A0(t0+2)->buf0 [last read ph1; +2]   ph4: B0(t0+2) [ph1; +3]
//   ph5: B1(t0+2)->buf0 [last read ph2; +3]   ph6: A1(t0+2) [ph3; +3]
//   ph7: A0(t1+2)->buf1 [last read ph5; +2]   ph8: B0(t1+2) [ph5; +3]
// RAW coverage, vmcnt(4) at ph4/ph8 (leaves the 2 newest stages in flight):
//   W4 lands <=ph2: A0,B0(t1)[ph7,8 prev] for ph5; B1(t1)[ph1] for ph6;
//                   A1(t1)[ph2] for ph7.
//   W8 lands <=ph6: A0,B0(t0+2)[ph3,4] for next ph1; B1(t0+2)[ph5] for next
//                   ph2; A1(t0+2)[ph6] for next ph3.
#define FENCE() asm volatile("" ::: "memory")
#define BAR()   do { FENCE(); __builtin_amdgcn_s_barrier(); FENCE(); } while (0)
#define VMW4()  asm volatile("s_waitcnt vmcnt(4)" ::: "memory")
#define VMW0()  asm volatile("s_waitcnt vmcnt(0)" ::: "memory")
#define LGW0()  asm volatile("s_waitcnt lgkmcnt(0)" ::: "memory")
#define SB0()   __builtin_amdgcn_sched_barrier(0)
#define PRIO1() __builtin_amdgcn_s_setprio(1)
#define PRIO0() __builtin_amdgcn_s_setprio(0)

// precomputed-address LDS read: vaddr VGPR + literal offset immediate
#define DSR(dst, va, IMM) \
    asm volatile("ds_read_b128 %0, %1 offset:" #IMM : "=v"(dst) : "v"(va))

__global__ __launch_bounds__(512, 2) void dora_gemm(
    const unsigned short* __restrict__ xbf,   // [8192][4096] bf16
    const unsigned short* __restrict__ wbf,   // [4096][4096] bf16
    const float* __restrict__ scale,          // [4096]
    float* __restrict__ out) {                // [8192][4096] fp32
    __shared__ __align__(16) unsigned short As[2][256 * 64];
    __shared__ __align__(16) unsigned short Bs[2][256 * 64];

    const int tid  = threadIdx.x;
    const int lane = tid & 63;
    const int w    = tid >> 6;     // wave 0..7
    const int wm   = w >> 2;       // 0..1
    const int wn   = w & 3;        // 0..3
    const int q    = lane >> 4;
    const int c15  = lane & 15;

    // XCD mapping: 8 XCDs x 64 blocks; each XCD owns an 8M x 8N tile square
    // (bijective over the 32x16 grid); M sweeps fastest within the square.
    const int bid = blockIdx.x;
    const int xcd = bid & 7, sub = bid >> 3;
    const int tileM = (((xcd & 3) << 3) | (sub & 7)) << 8;   // 0..31 * 256
    const int tileN = (((xcd >> 2) << 3) | (sub >> 3)) << 8; // 0..15 * 256

    // staging: thread t, load j covers linear chunk c = j*512 + t of a half-tile
    // (128 rows x 64 bf16). row-in-half = c>>3, phys 16B chunk = c&7; XOR swizzle:
    // phys chunk p of row r holds logical chunk p ^ (r&7) -> pre-swizzled source.
    const int r0 = tid >> 3;              // 0..63
    const int lc = (tid & 7) ^ (r0 & 7);
    const size_t aoff = (size_t)(tileM + r0) * 4096 + lc * 8;
    const size_t boff = (size_t)(tileN + r0) * 4096 + lc * 8;
    const int ld0 = (w * 64) * 8;         // shorts; wave-uniform LDS base, j=0
    const int ld1 = (512 + w * 64) * 8;   // j=1 (+64 rows)

#define STAGE_A(d, h, k0) do {                                                            \
    GLD_LDS16(xbf + aoff + (size_t)((h) * 128) * 4096 + (k0),      &As[d][(h) * 8192 + ld0]); \
    GLD_LDS16(xbf + aoff + (size_t)((h) * 128 + 64) * 4096 + (k0), &As[d][(h) * 8192 + ld1]); \
} while (0)
#define STAGE_B(d, h, k0) do {                                                            \
    GLD_LDS16(wbf + boff + (size_t)((h) * 128) * 4096 + (k0),      &Bs[d][(h) * 8192 + ld0]); \
    GLD_LDS16(wbf + boff + (size_t)((h) * 128 + 64) * 4096 + (k0), &Bs[d][(h) * 8192 + ld1]); \
} while (0)

    // Precomputed ds_read base addresses (buf0, mh0/nh0). For every frag,
    // row&7 == c15&7, so phys = (kc*4+q)^(c15&7) is row-independent.
    const int rb = c15 & 7;
    unsigned aA[4][2], aB[2][2];
#pragma unroll
    for (int mt = 0; mt < 4; ++mt)
#pragma unroll
        for (int kc = 0; kc < 2; ++kc)
            aA[mt][kc] = LDSOFF(&As[0][(wm * 64 + mt * 16 + c15) * 64 +
                                       ((kc * 4 + q) ^ rb) * 8]);
#pragma unroll
    for (int nt = 0; nt < 2; ++nt)
#pragma unroll
        for (int kc = 0; kc < 2; ++kc)
            aB[nt][kc] = LDSOFF(&Bs[0][(wn * 32 + nt * 16 + c15) * 64 +
                                       ((kc * 4 + q) ^ rb) * 8]);

    s16x8 af[4][2];      // A frags [mt][kc], current mh (held across 2 phases)
    s16x8 bfx[2][2][2];  // B frags [nh][nt][kc], fully resident per K-tile
    f32x4 acc[8][4] = {};

    // IMM encodes (buffer, half): buf = +32768, mh/nh = +16384
#define RD_A(IMM) do {                                                        \
    DSR(af[0][0], aA[0][0], IMM); DSR(af[0][1], aA[0][1], IMM);               \
    DSR(af[1][0], aA[1][0], IMM); DSR(af[1][1], aA[1][1], IMM);               \
    DSR(af[2][0], aA[2][0], IMM); DSR(af[2][1], aA[2][1], IMM);               \
    DSR(af[3][0], aA[3][0], IMM); DSR(af[3][1], aA[3][1], IMM); } while (0)
#define RD_B(nh, IMM) do {                                                    \
    DSR(bfx[nh][0][0], aB[0][0], IMM); DSR(bfx[nh][0][1], aB[0][1], IMM);     \
    DSR(bfx[nh][1][0], aB[1][0], IMM); DSR(bfx[nh][1][1], aB[1][1], IMM); } while (0)

#define MFMA_Q(mh, nh) do {                                                   \
    _Pragma("unroll") for (int mt = 0; mt < 4; ++mt)                          \
    _Pragma("unroll") for (int nt = 0; nt < 2; ++nt)                          \
    _Pragma("unroll") for (int kc = 0; kc < 2; ++kc)                          \
        acc[(mh) * 4 + mt][(nh) * 2 + nt] =                                   \
            __builtin_amdgcn_mfma_f32_16x16x32_bf16(                          \
                af[mt][kc], bfx[nh][nt][kc],                                  \
                acc[(mh) * 4 + mt][(nh) * 2 + nt], 0, 0, 0);                  \
} while (0)

    // prologue: tile0 {A0,B0,B1,A1} -> buf0; tile1 {A0,B0} -> buf1
    // (B1(t1)/A1(t1) are staged at ph1/ph2 of iter 0, per the steady ledger)
    STAGE_A(0, 0, 0); STAGE_B(0, 0, 0); STAGE_B(0, 1, 0); STAGE_A(0, 1, 0);
    STAGE_A(1, 0, 64); STAGE_B(1, 0, 64);
    VMW4(); BAR();   // tile0 landed; tile1's A0,B0 (4 loads) stay in flight

    for (int t0k = 0; t0k <= 60 * 64; t0k += 128) {  // t0=2i (0..60), t1=2i+1
        const int kt1 = t0k + 64;    // tile t1 (B1/A1 staged ph1/ph2)
        const int kn2 = t0k + 128;   // tile t0+2 -> buf0
        const int kn3 = t0k + 192;   // tile t1+2 -> buf1
        // ph1: Q(0,0) — 12 ds_read
        RD_A(0); RD_B(0, 0);
        STAGE_B(1, 1, kt1);
        BAR(); LGW0(); SB0();
        PRIO1(); MFMA_Q(0, 0); PRIO0();
        // ph2: Q(0,1) — 4 ds_read (A held)
        RD_B(1, 16384);
        STAGE_A(1, 1, kt1);
        BAR(); LGW0(); SB0();
        PRIO1(); MFMA_Q(0, 1); PRIO0();
        // ph3: Q(1,1) — 8 ds_read (B held)
        RD_A(16384);
        STAGE_A(0, 0, kn2);
        BAR(); LGW0(); SB0();
        PRIO1(); MFMA_Q(1, 1); PRIO0();
        // ph4: Q(1,0) — 0 ds_read; W4
        STAGE_B(0, 0, kn2);
        VMW4(); BAR();
        PRIO1(); MFMA_Q(1, 0); PRIO0();
        // ph5: Q(0,0) of t1 (buf1)
        RD_A(32768); RD_B(0, 32768);
        STAGE_B(0, 1, kn2);
        BAR(); LGW0(); SB0();
        PRIO1(); MFMA_Q(0, 0); PRIO0();
        // ph6: Q(0,1)
        RD_B(1, 49152);
        STAGE_A(0, 1, kn2);
        BAR(); LGW0(); SB0();
        PRIO1(); MFMA_Q(0, 1); PRIO0();
        // ph7: Q(1,1)
        RD_A(49152);
        STAGE_A(1, 0, kn3);
        BAR(); LGW0(); SB0();
        PRIO1(); MFMA_Q(1, 1); PRIO0();
        // ph8: Q(1,0); W8
        STAGE_B(1, 0, kn3);
        VMW4(); BAR();
        PRIO1(); MFMA_Q(1, 0); PRIO0();
    }

    // ---- peel: tiles 62 (buf0) / 63 (buf1) ----
    // entering: tile62 fully landed (W8 + BAR of last iter); A0,B0(63) in
    // flight (ph7/ph8 of last iter). Stage B1(63)/A1(63) here (steady ph1/ph2
    // pattern); no barriers needed until the pre-tile-63 full drain.
    RD_A(0); RD_B(0, 0);
    STAGE_B(1, 1, 4032);             // B1(63)
    LGW0(); SB0();
    PRIO1(); MFMA_Q(0, 0); PRIO0();
    RD_B(1, 16384);
    STAGE_A(1, 1, 4032);             // A1(63)
    LGW0(); SB0();
    PRIO1(); MFMA_Q(0, 1); PRIO0();
    RD_A(16384);
    LGW0(); SB0();
    PRIO1(); MFMA_Q(1, 1); MFMA_Q(1, 0); PRIO0();
    VMW0(); BAR();                   // all of tile 63 landed, all waves
    RD_A(32768); RD_B(0, 32768);
    LGW0(); SB0();
    PRIO1(); MFMA_Q(0, 0); PRIO0();
    RD_B(1, 49152);
    LGW0(); SB0();
    PRIO1(); MFMA_Q(0, 1); PRIO0();
    RD_A(49152);
    LGW0(); SB0();
    PRIO1(); MFMA_Q(1, 1); MFMA_Q(1, 0); PRIO0();

    // epilogue: C/D layout col=lane&15, row=(lane>>4)*4+reg ; scale by mag/norm
    // NT stores: C is write-once, never re-read -> don't evict hot bf16 operands.
#pragma unroll
    for (int nh = 0; nh < 2; ++nh)
#pragma unroll
    for (int nt = 0; nt < 2; ++nt) {
        const int col = tileN + nh * 128 + wn * 32 + nt * 16 + c15;
        const float s = scale[col];
#pragma unroll
        for (int mh = 0; mh < 2; ++mh)
#pragma unroll
        for (int mt = 0; mt < 4; ++mt) {
            const int row0 = tileM + mh * 128 + wm * 64 + mt * 16 + q * 4;
#pragma unroll
            for (int r = 0; r < 4; ++r)
                __builtin_nontemporal_store(
                    acc[mh * 4 + mt][nh * 2 + nt][r] * s,
                    &out[(size_t)(row0 + r) * 4096 + col]);
        }
    }
}

extern "C" void kernel_launch(void* const* d_in, const int* in_sizes, int n_in,
                              void* d_out, int out_size, void* d_ws, size_t ws_size,
                              hipStream_t stream) {
    const float* x   = (const float*)d_in[0];   // [4,2048,4096]
    const float* W   = (const float*)d_in[1];   // [4096,4096]
    const float* A   = (const float*)d_in[2];   // [16,4096]
    const float* B   = (const float*)d_in[3];   // [4096,16]
    const float* mag = (const float*)d_in[4];   // [4096]
    float* out = (float*)d_out;

    const size_t XBF_BYTES = (size_t)8192 * 4096 * 2;  // 67,108,864
    const size_t WBF_BYTES = (size_t)4096 * 4096 * 2;  // 33,554,432
    const size_t NEEDED = XBF_BYTES + WBF_BYTES + 4096 * sizeof(float);
    if (ws_size < NEEDED) return;

    unsigned short* xbf = (unsigned short*)d_ws;
    unsigned short* wbf = (unsigned short*)((char*)d_ws + XBF_BYTES);
    float* scale = (float*)((char*)d_ws + XBF_BYTES + WBF_BYTES);

    prologue_kernel<<<8704, 256, 0, stream>>>((const float4*)x, (us4*)xbf,
                                              (const float4*)W, (const float4*)A,
                                              B, mag, wbf, scale);
    dora_gemm<<<512, 512, 0, stream>>>(xbf, wbf, scale, out);
}

// Round 14
// 290.248 us; speedup vs baseline: 1.1120x; 1.0468x over previous
//
#include <hip/hip_runtime.h>
#include <hip/hip_bf16.h>
#include <stdint.h>

typedef __attribute__((ext_vector_type(8))) short s16x8;    // bf16 MFMA A/B frag (4 VGPRs)
typedef __attribute__((ext_vector_type(4))) float f32x4;    // MFMA C/D frag
typedef __attribute__((ext_vector_type(4))) unsigned short us4;

// ---- bf16 round-to-nearest-even (inputs are finite normals) ----
__device__ inline unsigned short bf_rne(float f) {
    union { float f; uint32_t u; } v; v.f = f;
    uint32_t u = v.u;
    u += 0x7FFFu + ((u >> 16) & 1u);
    return (unsigned short)(u >> 16);
}

// non-temporal 16B fp32 load (single-use streams: x-fp32, W-fp32) — measured
// ~10us faster prologue (R13 A/B); keeps cache for the hot bf16 operands.
__device__ inline float4 ntload4(const float4* p) {
    f32x4 v = __builtin_nontemporal_load((const f32x4*)p);
    return *(float4*)&v;
}

// async global->LDS, 16B per lane; LDS dst is wave-uniform base + lane*16
#define GLD_LDS16(gp, lp)                                                     \
    __builtin_amdgcn_global_load_lds(                                         \
        (const __attribute__((address_space(1))) void*)(gp),                  \
        (__attribute__((address_space(3))) void*)(lp), 16, 0, 0)

// generic (__shared__) pointer -> 32-bit LDS byte offset for ds_read vaddr
#define LDSOFF(p) ((unsigned)(uintptr_t)(__attribute__((address_space(3))) const void*)(p))

// ---------------- Fused prologue (R13 version: NT loads on x/W) ----------------
__global__ __launch_bounds__(256) void prologue_kernel(
    const float4* __restrict__ x4, us4* __restrict__ xbf4,
    const float4* __restrict__ W4,
    const float4* __restrict__ A4,   // [16][1024] float4 (reused 512x: cached)
    const float* __restrict__ B,     // [4096][16]
    const float* __restrict__ mag,   // [4096]
    unsigned short* __restrict__ wbf,
    float* __restrict__ scale) {
    const int tid = threadIdx.x;
    if (blockIdx.x < 512) {
        const int m0 = blockIdx.x * 8;
        __shared__ float Bs[8][16];
        __shared__ float red[32];
        if (tid < 128) Bs[tid >> 4][tid & 15] = B[m0 * 16 + tid];
        __syncthreads();
        float ss[8] = {};
        for (int c = tid; c < 1024; c += 256) {
            float4 a[16];
#pragma unroll
            for (int r = 0; r < 16; ++r) a[r] = A4[r * 1024 + c];
#pragma unroll
            for (int i = 0; i < 8; ++i) {
                float4 w = ntload4(&W4[(size_t)(m0 + i) * 1024 + c]);
#pragma unroll
                for (int r = 0; r < 16; ++r) {
                    const float br = Bs[i][r];
                    w.x += br * a[r].x; w.y += br * a[r].y;
                    w.z += br * a[r].z; w.w += br * a[r].w;
                }
                ss[i] += w.x * w.x + w.y * w.y + w.z * w.z + w.w * w.w;
                us4 o; o[0] = bf_rne(w.x); o[1] = bf_rne(w.y);
                o[2] = bf_rne(w.z); o[3] = bf_rne(w.w);
                *(us4*)&wbf[(size_t)(m0 + i) * 4096 + c * 4] = o;
            }
        }
        const int lane = tid & 63, wv = tid >> 6;
#pragma unroll
        for (int i = 0; i < 8; ++i) {
            float v = ss[i];
#pragma unroll
            for (int off = 32; off > 0; off >>= 1) v += __shfl_down(v, off, 64);
            if (lane == 0) red[wv * 8 + i] = v;
        }
        __syncthreads();
        if (tid < 8) {
            float tot = red[tid] + red[8 + tid] + red[16 + tid] + red[24 + tid];
            scale[m0 + tid] = mag[m0 + tid] / sqrtf(tot);
        }
    } else {
        const size_t base = (size_t)(blockIdx.x - 512) * 1024 + tid;
#pragma unroll
        for (int j = 0; j < 4; ++j) {
            const size_t idx = base + j * 256;
            float4 a = ntload4(&x4[idx]);
            us4 o;
            o[0] = bf_rne(a.x); o[1] = bf_rne(a.y);
            o[2] = bf_rne(a.z); o[3] = bf_rne(a.w);
            xbf4[idx] = o;
        }
    }
}

// ---------------- GEMM: C[8192][4096] = xbf @ wbf^T * scale ----------------
// Exact R5-best body (226.6us, MfmaUtil 56.4, 0 bank conflicts): 256x256
// tile, BK=64, 8 waves (2M x 4N), 16x16x32 MFMA, precomputed-address
// inline-asm ds_read_b128, ONE barrier per phase, vmcnt(4) at ph4/ph8.
// Regular C stores (R13 proved NT stores cost ~10us).
// Stage ledger (iter i, t0=2i, t1=2i+1):
//   ph1: B1(t1)->buf1   [buf1.B1 last read ph6 of iter i-1; +3]
//   ph2: A1(t1)->buf1   [last read ph7 i-1; +3]
//   ph3: A0(t0+2)->buf0 [last read ph1; +2]   ph4: B0(t0+2) [ph1; +3]
//   ph5: B1(t0+2)->buf0 [last read ph2; +3]   ph6: A1(t0+2) [ph3; +3]
//   ph7: A0(t1+2)->buf1 [last read ph5; +2]   ph8: B0(t1+2) [ph5; +3]
// RAW coverage, vmcnt(4) at ph4/ph8 (leaves the 2 newest stages in flight):
//   W4 lands <=ph2: A0,B0(t1)[ph7,8 prev] for ph5; B1(t1)[ph1] for ph6;
//                   A1(t1)[ph2] for ph7.
//   W8 lands <=ph6: A0,B0(t0+2)[ph3,4] for next ph1; B1(t0+2)[ph5] for next
//                   ph2; A1(t0+2)[ph6] for next ph3.
#define FENCE() asm volatile("" ::: "memory")
#define BAR()   do { FENCE(); __builtin_amdgcn_s_barrier(); FENCE(); } while (0)
#define VMW4()  asm volatile("s_waitcnt vmcnt(4)" ::: "memory")
#define VMW0()  asm volatile("s_waitcnt vmcnt(0)" ::: "memory")
#define LGW0()  asm volatile("s_waitcnt lgkmcnt(0)" ::: "memory")
#define SB0()   __builtin_amdgcn_sched_barrier(0)
#define PRIO1() __builtin_amdgcn_s_setprio(1)
#define PRIO0() __builtin_amdgcn_s_setprio(0)

// precomputed-address LDS read: vaddr VGPR + literal offset immediate
#define DSR(dst, va, IMM) \
    asm volatile("ds_read_b128 %0, %1 offset:" #IMM : "=v"(dst) : "v"(va))

__global__ __launch_bounds__(512, 2) void dora_gemm(
    const unsigned short* __restrict__ xbf,   // [8192][4096] bf16
    const unsigned short* __restrict__ wbf,   // [4096][4096] bf16
    const float* __restrict__ scale,          // [4096]
    float* __restrict__ out) {                // [8192][4096] fp32
    __shared__ __align__(16) unsigned short As[2][256 * 64];
    __shared__ __align__(16) unsigned short Bs[2][256 * 64];

    const int tid  = threadIdx.x;
    const int lane = tid & 63;
    const int w    = tid >> 6;     // wave 0..7
    const int wm   = w >> 2;       // 0..1
    const int wn   = w & 3;        // 0..3
    const int q    = lane >> 4;
    const int c15  = lane & 15;

    // XCD mapping: 8 XCDs x 64 blocks; each XCD owns an 8M x 8N tile square
    // (bijective over the 32x16 grid); M sweeps fastest within the square.
    const int bid = blockIdx.x;
    const int xcd = bid & 7, sub = bid >> 3;
    const int tileM = (((xcd & 3) << 3) | (sub & 7)) << 8;   // 0..31 * 256
    const int tileN = (((xcd >> 2) << 3) | (sub >> 3)) << 8; // 0..15 * 256

    // staging: thread t, load j covers linear chunk c = j*512 + t of a half-tile
    // (128 rows x 64 bf16). row-in-half = c>>3, phys 16B chunk = c&7; XOR swizzle:
    // phys chunk p of row r holds logical chunk p ^ (r&7) -> pre-swizzled source.
    const int r0 = tid >> 3;              // 0..63
    const int lc = (tid & 7) ^ (r0 & 7);
    const size_t aoff = (size_t)(tileM + r0) * 4096 + lc * 8;
    const size_t boff = (size_t)(tileN + r0) * 4096 + lc * 8;
    const int ld0 = (w * 64) * 8;         // shorts; wave-uniform LDS base, j=0
    const int ld1 = (512 + w * 64) * 8;   // j=1 (+64 rows)

#define STAGE_A(d, h, k0) do {                                                            \
    GLD_LDS16(xbf + aoff + (size_t)((h) * 128) * 4096 + (k0),      &As[d][(h) * 8192 + ld0]); \
    GLD_LDS16(xbf + aoff + (size_t)((h) * 128 + 64) * 4096 + (k0), &As[d][(h) * 8192 + ld1]); \
} while (0)
#define STAGE_B(d, h, k0) do {                                                            \
    GLD_LDS16(wbf + boff + (size_t)((h) * 128) * 4096 + (k0),      &Bs[d][(h) * 8192 + ld0]); \
    GLD_LDS16(wbf + boff + (size_t)((h) * 128 + 64) * 4096 + (k0), &Bs[d][(h) * 8192 + ld1]); \
} while (0)

    // Precomputed ds_read base addresses (buf0, mh0/nh0). For every frag,
    // row&7 == c15&7, so phys = (kc*4+q)^(c15&7) is row-independent.
    const int rb = c15 & 7;
    unsigned aA[4][2], aB[2][2];
#pragma unroll
    for (int mt = 0; mt < 4; ++mt)
#pragma unroll
        for (int kc = 0; kc < 2; ++kc)
            aA[mt][kc] = LDSOFF(&As[0][(wm * 64 + mt * 16 + c15) * 64 +
                                       ((kc * 4 + q) ^ rb) * 8]);
#pragma unroll
    for (int nt = 0; nt < 2; ++nt)
#pragma unroll
        for (int kc = 0; kc < 2; ++kc)
            aB[nt][kc] = LDSOFF(&Bs[0][(wn * 32 + nt * 16 + c15) * 64 +
                                       ((kc * 4 + q) ^ rb) * 8]);

    s16x8 af[4][2];      // A frags [mt][kc], current mh (held across 2 phases)
    s16x8 bfx[2][2][2];  // B frags [nh][nt][kc], fully resident per K-tile
    f32x4 acc[8][4] = {};

    // IMM encodes (buffer, half): buf = +32768, mh/nh = +16384
#define RD_A(IMM) do {                                                        \
    DSR(af[0][0], aA[0][0], IMM); DSR(af[0][1], aA[0][1], IMM);               \
    DSR(af[1][0], aA[1][0], IMM); DSR(af[1][1], aA[1][1], IMM);               \
    DSR(af[2][0], aA[2][0], IMM); DSR(af[2][1], aA[2][1], IMM);               \
    DSR(af[3][0], aA[3][0], IMM); DSR(af[3][1], aA[3][1], IMM); } while (0)
#define RD_B(nh, IMM) do {                                                    \
    DSR(bfx[nh][0][0], aB[0][0], IMM); DSR(bfx[nh][0][1], aB[0][1], IMM);     \
    DSR(bfx[nh][1][0], aB[1][0], IMM); DSR(bfx[nh][1][1], aB[1][1], IMM); } while (0)

#define MFMA_Q(mh, nh) do {                                                   \
    _Pragma("unroll") for (int mt = 0; mt < 4; ++mt)                          \
    _Pragma("unroll") for (int nt = 0; nt < 2; ++nt)                          \
    _Pragma("unroll") for (int kc = 0; kc < 2; ++kc)                          \
        acc[(mh) * 4 + mt][(nh) * 2 + nt] =                                   \
            __builtin_amdgcn_mfma_f32_16x16x32_bf16(                          \
                af[mt][kc], bfx[nh][nt][kc],                                  \
                acc[(mh) * 4 + mt][(nh) * 2 + nt], 0, 0, 0);                  \
} while (0)

    // prologue: tile0 {A0,B0,B1,A1} -> buf0; tile1 {A0,B0} -> buf1
    // (B1(t1)/A1(t1) are staged at ph1/ph2 of iter 0, per the steady ledger)
    STAGE_A(0, 0, 0); STAGE_B(0, 0, 0); STAGE_B(0, 1, 0); STAGE_A(0, 1, 0);
    STAGE_A(1, 0, 64); STAGE_B(1, 0, 64);
    VMW4(); BAR();   // tile0 landed; tile1's A0,B0 (4 loads) stay in flight

    for (int t0k = 0; t0k <= 60 * 64; t0k += 128) {  // t0=2i (0..60), t1=2i+1
        const int kt1 = t0k + 64;    // tile t1 (B1/A1 staged ph1/ph2)
        const int kn2 = t0k + 128;   // tile t0+2 -> buf0
        const int kn3 = t0k + 192;   // tile t1+2 -> buf1
        // ph1: Q(0,0) — 12 ds_read
        RD_A(0); RD_B(0, 0);
        STAGE_B(1, 1, kt1);
        BAR(); LGW0(); SB0();
        PRIO1(); MFMA_Q(0, 0); PRIO0();
        // ph2: Q(0,1) — 4 ds_read (A held)
        RD_B(1, 16384);
        STAGE_A(1, 1, kt1);
        BAR(); LGW0(); SB0();
        PRIO1(); MFMA_Q(0, 1); PRIO0();
        // ph3: Q(1,1) — 8 ds_read (B held)
        RD_A(16384);
        STAGE_A(0, 0, kn2);
        BAR(); LGW0(); SB0();
        PRIO1(); MFMA_Q(1, 1); PRIO0();
        // ph4: Q(1,0) — 0 ds_read; W4
        STAGE_B(0, 0, kn2);
        VMW4(); BAR();
        PRIO1(); MFMA_Q(1, 0); PRIO0();
        // ph5: Q(0,0) of t1 (buf1)
        RD_A(32768); RD_B(0, 32768);
        STAGE_B(0, 1, kn2);
        BAR(); LGW0(); SB0();
        PRIO1(); MFMA_Q(0, 0); PRIO0();
        // ph6: Q(0,1)
        RD_B(1, 49152);
        STAGE_A(0, 1, kn2);
        BAR(); LGW0(); SB0();
        PRIO1(); MFMA_Q(0, 1); PRIO0();
        // ph7: Q(1,1)
        RD_A(49152);
        STAGE_A(1, 0, kn3);
        BAR(); LGW0(); SB0();
        PRIO1(); MFMA_Q(1, 1); PRIO0();
        // ph8: Q(1,0); W8
        STAGE_B(1, 0, kn3);
        VMW4(); BAR();
        PRIO1(); MFMA_Q(1, 0); PRIO0();
    }

    // ---- peel: tiles 62 (buf0) / 63 (buf1) ----
    // entering: tile62 fully landed (W8 + BAR of last iter); A0,B0(63) in
    // flight (ph7/ph8 of last iter). Stage B1(63)/A1(63) here (steady ph1/ph2
    // pattern); no barriers needed until the pre-tile-63 full drain.
    RD_A(0); RD_B(0, 0);
    STAGE_B(1, 1, 4032);             // B1(63)
    LGW0(); SB0();
    PRIO1(); MFMA_Q(0, 0); PRIO0();
    RD_B(1, 16384);
    STAGE_A(1, 1, 4032);             // A1(63)
    LGW0(); SB0();
    PRIO1(); MFMA_Q(0, 1); PRIO0();
    RD_A(16384);
    LGW0(); SB0();
    PRIO1(); MFMA_Q(1, 1); MFMA_Q(1, 0); PRIO0();
    VMW0(); BAR();                   // all of tile 63 landed, all waves
    RD_A(32768); RD_B(0, 32768);
    LGW0(); SB0();
    PRIO1(); MFMA_Q(0, 0); PRIO0();
    RD_B(1, 49152);
    LGW0(); SB0();
    PRIO1(); MFMA_Q(0, 1); PRIO0();
    RD_A(49152);
    LGW0(); SB0();
    PRIO1(); MFMA_Q(1, 1); MFMA_Q(1, 0); PRIO0();

    // epilogue: C/D layout col=lane&15, row=(lane>>4)*4+reg ; scale by mag/norm
#pragma unroll
    for (int nh = 0; nh < 2; ++nh)
#pragma unroll
    for (int nt = 0; nt < 2; ++nt) {
        const int col = tileN + nh * 128 + wn * 32 + nt * 16 + c15;
        const float s = scale[col];
#pragma unroll
        for (int mh = 0; mh < 2; ++mh)
#pragma unroll
        for (int mt = 0; mt < 4; ++mt) {
            const int row0 = tileM + mh * 128 + wm * 64 + mt * 16 + q * 4;
#pragma unroll
            for (int r = 0; r < 4; ++r)
                out[(size_t)(row0 + r) * 4096 + col] = acc[mh * 4 + mt][nh * 2 + nt][r] * s;
        }
    }
}

extern "C" void kernel_launch(void* const* d_in, const int* in_sizes, int n_in,
                              void* d_out, int out_size, void* d_ws, size_t ws_size,
                              hipStream_t stream) {
    const float* x   = (const float*)d_in[0];   // [4,2048,4096]
    const float* W   = (const float*)d_in[1];   // [4096,4096]
    const float* A   = (const float*)d_in[2];   // [16,4096]
    const float* B   = (const float*)d_in[3];   // [4096,16]
    const float* mag = (const float*)d_in[4];   // [4096]
    float* out = (float*)d_out;

    const size_t XBF_BYTES = (size_t)8192 * 4096 * 2;  // 67,108,864
    const size_t WBF_BYTES = (size_t)4096 * 4096 * 2;  // 33,554,432
    const size_t NEEDED = XBF_BYTES + WBF_BYTES + 4096 * sizeof(float);
    if (ws_size < NEEDED) return;

    unsigned short* xbf = (unsigned short*)d_ws;
    unsigned short* wbf = (unsigned short*)((char*)d_ws + XBF_BYTES);
    float* scale = (float*)((char*)d_ws + XBF_BYTES + WBF_BYTES);

    prologue_kernel<<<8704, 256, 0, stream>>>((const float4*)x, (us4*)xbf,
                                              (const float4*)W, (const float4*)A,
                                              B, mag, wbf, scale);
    dora_gemm<<<512, 512, 0, stream>>>(xbf, wbf, scale, out);
}